// Round 7
// baseline (726.318 us; speedup 1.0000x reference)
//
#include <hip/hip_runtime.h>
#include <hip/hip_fp16.h>

// Problem constants: B=16, S=512, HID=512, NH=8, DK=64, TH=32, TE=16, scale=1/8

typedef __attribute__((ext_vector_type(8))) __bf16 bf16x8;
typedef __attribute__((ext_vector_type(8))) _Float16 f16x8;
typedef __attribute__((ext_vector_type(4))) float f32x4;

static __device__ __forceinline__ unsigned short f2bf(float f) {
  unsigned u = __float_as_uint(f);
  unsigned r = (u + 0x7fffu + ((u >> 16) & 1u)) >> 16;   // RNE
  return (unsigned short)r;
}
static __device__ __forceinline__ unsigned short f2h(float f) {
  _Float16 h = (_Float16)f;
  return __builtin_bit_cast(unsigned short, h);
}
static __device__ __forceinline__ float h2f(unsigned short u) {
  _Float16 h = __builtin_bit_cast(_Float16, u);
  return (float)h;
}

// ---------------------------------------------------------------------------
// fp32 -> bf16 convert for GEMM inputs: q,k,v and Wq,Wk,Wv,Wo.
// ---------------------------------------------------------------------------
__global__ __launch_bounds__(256) void convert_bf16(
    const float* __restrict__ q, const float* __restrict__ k,
    const float* __restrict__ v, const float* __restrict__ Wq,
    const float* __restrict__ Wk, const float* __restrict__ Wv,
    const float* __restrict__ Wo,
    unsigned short* __restrict__ qb, unsigned short* __restrict__ kb,
    unsigned short* __restrict__ vb, unsigned short* __restrict__ wqb,
    unsigned short* __restrict__ wkb, unsigned short* __restrict__ wvb,
    unsigned short* __restrict__ wob)
{
  const int bid = blockIdx.x;
  const float* src; unsigned short* dst; long blk;
  if (bid < 4096)        { src = q;  dst = qb; blk = bid; }
  else if (bid < 8192)   { src = k;  dst = kb; blk = bid - 4096; }
  else if (bid < 12288)  { src = v;  dst = vb; blk = bid - 8192; }
  else {
    int r = bid - 12288; int w = r >> 8; blk = r & 255;
    src = (w == 0) ? Wq : (w == 1) ? Wk : (w == 2) ? Wv : Wo;
    dst = (w == 0) ? wqb : (w == 1) ? wkb : (w == 2) ? wvb : wob;
  }
  size_t base = (size_t)blk * 1024 + threadIdx.x * 4;
  float4 f = *reinterpret_cast<const float4*>(&src[base]);
  ushort4 o; o.x = f2bf(f.x); o.y = f2bf(f.y); o.z = f2bf(f.z); o.w = f2bf(f.w);
  *reinterpret_cast<ushort4*>(&dst[base]) = o;
}

// ---------------------------------------------------------------------------
// pack_idx: precompute packed (t | e<<8) in C-fragment order, once per (b,it).
// Cell = (b*8+it)*16+jc holds 4 waves x 64 lanes x 8 u16 = 4 KB.
// Grid 2048 blocks x 64 threads: one wave per cell.
// ---------------------------------------------------------------------------
__global__ __launch_bounds__(64) void pack_idx(
    const int* __restrict__ dist, const int* __restrict__ edge,
    unsigned short* __restrict__ pidx)
{
  const int cell = blockIdx.x;          // (b*8+it)*16 + jc
  const int jc = cell & 15;
  const int bit = cell >> 4;            // b*8+it
  const int b = bit >> 3, it = bit & 7;
  const int lane = threadIdx.x;
  const int quad = lane >> 4, l15 = lane & 15;
  unsigned short out[4][8];
  #pragma unroll
  for (int w = 0; w < 4; w++) {
    #pragma unroll
    for (int tile = 0; tile < 2; tile++) {
      #pragma unroll
      for (int r = 0; r < 4; r++) {
        int i = it*64 + w*16 + quad*4 + r;
        int j = jc*32 + tile*16 + l15;
        size_t g = ((size_t)(b*512) + i)*512 + j;
        int t = dist[g], e = edge[g];
        out[w][tile*4 + r] = (unsigned short)(t | (e << 8));
      }
    }
  }
  #pragma unroll
  for (int w = 0; w < 4; w++) {
    size_t base = (size_t)cell*2048 + (w*64 + lane)*8;
    *reinterpret_cast<uint4*>(&pidx[base]) = *reinterpret_cast<uint4*>(&out[w][0]);
  }
}

// ---------------------------------------------------------------------------
// bf16 MFMA GEMM (Q/K proj): Y = f16 head-major [B,H,S,64].
// ---------------------------------------------------------------------------
__global__ __launch_bounds__(256) void proj_qk(
    const unsigned short* __restrict__ X, const unsigned short* __restrict__ W,
    const float* __restrict__ bias, unsigned short* __restrict__ Y)
{
  __shared__ unsigned short As[128][40];
  __shared__ unsigned short Bs[128][40];
  const int tid = threadIdx.x;
  const int m0 = blockIdx.x * 128;
  const int n0 = blockIdx.y * 128;
  const int lane = tid & 63;
  const int w = tid >> 6;
  const int wr = w >> 1, wc = w & 1;
  const int l15 = lane & 15, quad = lane >> 4;

  const int srow = tid & 127;
  const unsigned short* srcrow = (tid < 128) ? &X[(size_t)(m0 + srow) * 512]
                                             : &W[(size_t)(n0 + srow) * 512];
  unsigned short* dstrow = (tid < 128) ? As[srow] : Bs[srow];

  f32x4 acc[4][4];
  #pragma unroll
  for (int i = 0; i < 4; i++)
    #pragma unroll
    for (int j = 0; j < 4; j++) acc[i][j] = (f32x4){0.f, 0.f, 0.f, 0.f};

  for (int k0 = 0; k0 < 512; k0 += 32) {
    #pragma unroll
    for (int u = 0; u < 4; u++) {
      uint4 t4 = *reinterpret_cast<const uint4*>(&srcrow[k0 + u * 8]);
      *reinterpret_cast<uint4*>(&dstrow[u * 8]) = t4;
    }
    __syncthreads();
    bf16x8 af[4], bfr[4];
    #pragma unroll
    for (int mt = 0; mt < 4; mt++)
      af[mt] = *reinterpret_cast<const bf16x8*>(&As[wr * 64 + mt * 16 + l15][quad * 8]);
    #pragma unroll
    for (int nt = 0; nt < 4; nt++)
      bfr[nt] = *reinterpret_cast<const bf16x8*>(&Bs[wc * 64 + nt * 16 + l15][quad * 8]);
    #pragma unroll
    for (int mt = 0; mt < 4; mt++)
      #pragma unroll
      for (int nt = 0; nt < 4; nt++)
        acc[mt][nt] = __builtin_amdgcn_mfma_f32_16x16x32_bf16(
            af[mt], bfr[nt], acc[mt][nt], 0, 0, 0);
    __syncthreads();
  }

  float bn[4];
  #pragma unroll
  for (int nt = 0; nt < 4; nt++)
    bn[nt] = bias[n0 + wc * 64 + nt * 16 + l15];
  #pragma unroll
  for (int mt = 0; mt < 4; mt++) {
    #pragma unroll
    for (int r = 0; r < 4; r++) {
      int m = m0 + wr * 64 + mt * 16 + quad * 4 + r;
      int bb = m >> 9, s = m & 511;
      #pragma unroll
      for (int nt = 0; nt < 4; nt++) {
        int n = n0 + wc * 64 + nt * 16 + l15;
        int h = n >> 6, d = n & 63;
        Y[(((size_t)(bb * 8 + h) * 512) + s) * 64 + d] = f2h(acc[mt][nt][r] + bn[nt]);
      }
    }
  }
}

// ---------------------------------------------------------------------------
// V proj: writes f16 TRANSPOSED+TILED vht[bh][16 chunk][64 d][32 jj].
// ---------------------------------------------------------------------------
__global__ __launch_bounds__(256) void proj_v(
    const unsigned short* __restrict__ X, const unsigned short* __restrict__ W,
    const float* __restrict__ bias, unsigned short* __restrict__ Y)
{
  __shared__ unsigned short As[128][40];
  __shared__ unsigned short Bs[128][40];
  const int tid = threadIdx.x;
  const int m0 = blockIdx.x * 128;
  const int n0 = blockIdx.y * 128;
  const int lane = tid & 63;
  const int w = tid >> 6;
  const int wr = w >> 1, wc = w & 1;
  const int l15 = lane & 15, quad = lane >> 4;

  const int srow = tid & 127;
  const unsigned short* srcrow = (tid < 128) ? &X[(size_t)(m0 + srow) * 512]
                                             : &W[(size_t)(n0 + srow) * 512];
  unsigned short* dstrow = (tid < 128) ? As[srow] : Bs[srow];

  f32x4 acc[4][4];
  #pragma unroll
  for (int i = 0; i < 4; i++)
    #pragma unroll
    for (int j = 0; j < 4; j++) acc[i][j] = (f32x4){0.f, 0.f, 0.f, 0.f};

  for (int k0 = 0; k0 < 512; k0 += 32) {
    #pragma unroll
    for (int u = 0; u < 4; u++) {
      uint4 t4 = *reinterpret_cast<const uint4*>(&srcrow[k0 + u * 8]);
      *reinterpret_cast<uint4*>(&dstrow[u * 8]) = t4;
    }
    __syncthreads();
    bf16x8 af[4], bfr[4];
    #pragma unroll
    for (int mt = 0; mt < 4; mt++)
      af[mt] = *reinterpret_cast<const bf16x8*>(&As[wr * 64 + mt * 16 + l15][quad * 8]);
    #pragma unroll
    for (int nt = 0; nt < 4; nt++)
      bfr[nt] = *reinterpret_cast<const bf16x8*>(&Bs[wc * 64 + nt * 16 + l15][quad * 8]);
    #pragma unroll
    for (int mt = 0; mt < 4; mt++)
      #pragma unroll
      for (int nt = 0; nt < 4; nt++)
        acc[mt][nt] = __builtin_amdgcn_mfma_f32_16x16x32_bf16(
            af[mt], bfr[nt], acc[mt][nt], 0, 0, 0);
    __syncthreads();
  }

  float bn[4];
  #pragma unroll
  for (int nt = 0; nt < 4; nt++)
    bn[nt] = bias[n0 + wc * 64 + nt * 16 + l15];
  #pragma unroll
  for (int mt = 0; mt < 4; mt++) {
    #pragma unroll
    for (int r = 0; r < 4; r++) {
      int m = m0 + wr * 64 + mt * 16 + quad * 4 + r;
      int bb = m >> 9, s = m & 511;
      #pragma unroll
      for (int nt = 0; nt < 4; nt++) {
        int n = n0 + wc * 64 + nt * 16 + l15;
        int h = n >> 6, d = n & 63;
        size_t bh = (size_t)(bb * 8 + h);
        Y[(bh * 16 + (s >> 5)) * 2048 + d * 32 + (s & 31)] = f2h(acc[mt][nt][r] + bn[nt]);
      }
    }
  }
}

// ---------------------------------------------------------------------------
// Bias tables (f16 q/k inputs), block = (bh, quarter of rows). 512 blocks.
// ---------------------------------------------------------------------------
__global__ __launch_bounds__(256) void table_kernel(
    const unsigned short* __restrict__ qh16, const unsigned short* __restrict__ kh16,
    const float* __restrict__ qhe, const float* __restrict__ qee,
    const float* __restrict__ khe, const float* __restrict__ kee,
    float* __restrict__ Aq, float* __restrict__ QKe,
    float* __restrict__ Bkh)
{
  const int bh = blockIdx.x >> 2;
  const int part = blockIdx.x & 3;
  const int h = bh & 7;
  const int tid = threadIdx.x;
  __shared__ float qhe_s[32][65];
  __shared__ float qee_s[16][65];
  __shared__ float khe_s[32][65];
  __shared__ float kee_s[16][65];
  __shared__ float qrow[8][68];
  __shared__ float krow[8][68];
  for (int idx = tid; idx < 96*64; idx += 256) {
    int r = idx >> 6, d = idx & 63;
    if (r < 32)      qhe_s[r][d]    = qhe[r*512 + h*64 + d];
    else if (r < 48) qee_s[r-32][d] = qee[(r-32)*512 + h*64 + d];
    else if (r < 80) khe_s[r-48][d] = khe[(r-48)*512 + h*64 + d];
    else             kee_s[r-80][d] = kee[(r-80)*512 + h*64 + d];
  }
  __syncthreads();
  const int which = tid >> 7;
  const int rem = tid & 127;
  const int lr = rem >> 4;
  const int ldp = (rem & 15) * 4;
  const int il = tid >> 5;
  const int t  = tid & 31;
  const int bhS = bh * 512;
  for (int i0 = part*128; i0 < part*128 + 128; i0 += 8) {
    {
      const unsigned short* src = which ? kh16 : qh16;
      ushort4 v4 = *reinterpret_cast<const ushort4*>(&src[(bhS + i0 + lr)*64 + ldp]);
      float* dst = which ? &krow[lr][ldp] : &qrow[lr][ldp];
      dst[0] = h2f(v4.x); dst[1] = h2f(v4.y); dst[2] = h2f(v4.z); dst[3] = h2f(v4.w);
    }
    __syncthreads();
    float accq = 0.f, acck = 0.f;
    #pragma unroll 8
    for (int d = 0; d < 64; d++) {
      accq = fmaf(qrow[il][d], qhe_s[t][d], accq);
      acck = fmaf(krow[il][d], khe_s[t][d], acck);
    }
    Aq[(bhS + i0 + il)*32 + t] = accq;
    Bkh[(bhS + i0 + il)*32 + t] = acck;
    if (t < 16) {
      float aq2 = 0.f, ak2 = 0.f;
      #pragma unroll 8
      for (int d = 0; d < 64; d++) {
        aq2 = fmaf(qrow[il][d], qee_s[t][d], aq2);
        ak2 = fmaf(krow[il][d], kee_s[t][d], ak2);
      }
      QKe[(bhS + i0 + il)*16 + t] = aq2 + ak2;
    }
    __syncthreads();
  }
}

// ---------------------------------------------------------------------------
// Fused MFMA attention v5. Block = (bh, 64-row tile), 256 thr, 4 blocks/CU.
//  - packed idx loaded from global in C-frag order (pack_idx) -> registers;
//    the 3 table gathers per element are now independent ds_read_u16s
//  - embT overlays the dead K/V LDS in the epilogue (LDS 38.4 KB)
//  - Vts/Pp/Ks strides padded to kill 8-way b128 conflicts
// ---------------------------------------------------------------------------
__global__ __launch_bounds__(256, 4) void attn_mfma(
    const unsigned short* __restrict__ qh16, const unsigned short* __restrict__ kh16,
    const unsigned short* __restrict__ vht,
    const float* __restrict__ Aq, const float* __restrict__ QKe,
    const float* __restrict__ Bkh,
    const float* __restrict__ vhe, const float* __restrict__ vee,
    const unsigned short* __restrict__ pidx,
    unsigned short* __restrict__ outp_bf)
{
  const int blk = blockIdx.x;
  const int rt = blk & 7;
  const int bh = blk >> 3;
  const int b = bh >> 3, h = bh & 7;
  const int i0 = rt * 64;
  const int tid = threadIdx.x;
  const int w = tid >> 6;
  const int lane = tid & 63;
  const int l15 = lane & 15, quad = lane >> 4;
  const int bhS = bh * 512;

  __shared__ unsigned short kvArea[5248];   // 10496 B: Ks[32][76] + Vts[64][44] | embT[64][76]
  __shared__ unsigned short Pp[4][16][44];  //  5632
  __shared__ unsigned short Aqs[64][36];    //  4608  f16
  __shared__ unsigned short bkh_s[32][36];  //  2304  f16
  __shared__ unsigned short QKes[64][20];   //  2560  f16
  __shared__ float vatt[64][33];            //  8448
  __shared__ float veatt[64][17];           //  4352   -> total 38,400 B

  unsigned short (*Ks)[76]  = (unsigned short (*)[76])kvArea;
  unsigned short (*Vts)[44] = (unsigned short (*)[44])(kvArea + 32*76);
  unsigned short (*embT)[76]= (unsigned short (*)[76])kvArea;

  // ---- Phase A staging
  {
    int r = tid >> 2, t8 = (tid & 3) * 8;           // Aqs: 64x32 f32 -> f16
    float4 a0 = *reinterpret_cast<const float4*>(&Aq[(bhS + i0 + r)*32 + t8]);
    float4 a1 = *reinterpret_cast<const float4*>(&Aq[(bhS + i0 + r)*32 + t8 + 4]);
    ushort4 u0; u0.x = f2h(a0.x); u0.y = f2h(a0.y); u0.z = f2h(a0.z); u0.w = f2h(a0.w);
    ushort4 u1; u1.x = f2h(a1.x); u1.y = f2h(a1.y); u1.z = f2h(a1.z); u1.w = f2h(a1.w);
    *reinterpret_cast<ushort4*>(&Aqs[r][t8]) = u0;
    *reinterpret_cast<ushort4*>(&Aqs[r][t8 + 4]) = u1;
  }
  {
    int r = tid >> 2, t4 = (tid & 3) * 4;           // QKes: 64x16
    float4 a0 = *reinterpret_cast<const float4*>(&QKe[(bhS + i0 + r)*16 + t4]);
    ushort4 u0; u0.x = f2h(a0.x); u0.y = f2h(a0.y); u0.z = f2h(a0.z); u0.w = f2h(a0.w);
    *reinterpret_cast<ushort4*>(&QKes[r][t4]) = u0;
  }
  for (int idx = tid; idx < 64*33; idx += 256) (&vatt[0][0])[idx] = 0.f;
  for (int idx = tid; idx < 64*17; idx += 256) (&veatt[0][0])[idx] = 0.f;

  // q A-fragments from global
  f16x8 aq0 = *reinterpret_cast<const f16x8*>(&qh16[(size_t)(bhS + i0 + w*16 + l15)*64 + quad*8]);
  f16x8 aq1 = *reinterpret_cast<const f16x8*>(&qh16[(size_t)(bhS + i0 + w*16 + l15)*64 + 32 + quad*8]);
  __syncthreads();

  const size_t pBase = ((size_t)(b*8 + rt)*16)*2048 + tid*8;
  f32x4 Oacc[4];
  #pragma unroll
  for (int nt = 0; nt < 4; nt++) Oacc[nt] = (f32x4){0.f,0.f,0.f,0.f};
  float sum4[4] = {0.f, 0.f, 0.f, 0.f};

  #pragma unroll 1
  for (int jc = 0; jc < 16; jc++) {
    const int j0 = jc * 32;
    {   // K rows: 32 x 64 f16
      int r = tid >> 3, c8 = (tid & 7) * 8;
      uint4 kv = *reinterpret_cast<const uint4*>(&kh16[(size_t)(bhS + j0 + r)*64 + c8]);
      *reinterpret_cast<uint4*>(&Ks[r][c8]) = kv;
    }
    {   // V^T chunk: contiguous 4 KB
      int d = tid >> 2, c8 = (tid & 3) * 8;
      uint4 vv = *reinterpret_cast<const uint4*>(&vht[((size_t)bh*16 + jc)*2048 + d*32 + c8]);
      *reinterpret_cast<uint4*>(&Vts[d][c8]) = vv;
    }
    {   // bkh chunk: 32x32 f32 -> f16
      int r = tid >> 3, t4 = (tid & 7) * 4;
      float4 b4 = *reinterpret_cast<const float4*>(&Bkh[(bhS + j0 + r)*32 + t4]);
      ushort4 u; u.x = f2h(b4.x); u.y = f2h(b4.y); u.z = f2h(b4.z); u.w = f2h(b4.w);
      *reinterpret_cast<ushort4*>(&bkh_s[r][t4]) = u;
    }
    // packed indices for this thread's 8 C-elements (coalesced 16B load)
    uint4 praw = *reinterpret_cast<const uint4*>(&pidx[pBase + jc*2048]);
    const unsigned short* pk = reinterpret_cast<const unsigned short*>(&praw);
    __syncthreads();

    // QK via MFMA + scalar bias/exp/atomics, 2 key tiles of 16
    #pragma unroll
    for (int tile = 0; tile < 2; tile++) {
      f16x8 bk0 = *reinterpret_cast<const f16x8*>(&Ks[tile*16 + l15][quad*8]);
      f16x8 bk1 = *reinterpret_cast<const f16x8*>(&Ks[tile*16 + l15][32 + quad*8]);
      f32x4 sacc = (f32x4){0.f,0.f,0.f,0.f};
      sacc = __builtin_amdgcn_mfma_f32_16x16x32_f16(aq0, bk0, sacc, 0, 0, 0);
      sacc = __builtin_amdgcn_mfma_f32_16x16x32_f16(aq1, bk1, sacc, 0, 0, 0);
      const int jloc = tile*16 + l15;
      #pragma unroll
      for (int r = 0; r < 4; r++) {
        const int iloc = w*16 + quad*4 + r;
        unsigned u = pk[tile*4 + r];
        int t = u & 31, e = u >> 8;
        float s = (sacc[r] + h2f(Aqs[iloc][t]) + h2f(bkh_s[jloc][t])
                   + h2f(QKes[iloc][e])) * 0.125f;
        float p = __expf(fminf(s, 10.f));
        sum4[r] += p;
        atomicAdd(&vatt[iloc][t], p);
        atomicAdd(&veatt[iloc][e], p);
        Pp[w][quad*4 + r][jloc] = f2h(p);
      }
    }

    // PV via MFMA (K=32 over this chunk)
    {
      f16x8 ap = *reinterpret_cast<const f16x8*>(&Pp[w][l15][quad*8]);
      #pragma unroll
      for (int nt = 0; nt < 4; nt++) {
        f16x8 bv = *reinterpret_cast<const f16x8*>(&Vts[nt*16 + l15][quad*8]);
        Oacc[nt] = __builtin_amdgcn_mfma_f32_16x16x32_f16(ap, bv, Oacc[nt], 0, 0, 0);
      }
    }
    __syncthreads();
  }

  // row sums -> 1/sum
  float ri[4];
  #pragma unroll
  for (int r = 0; r < 4; r++) {
    float s = sum4[r];
    #pragma unroll
    for (int off = 1; off < 16; off <<= 1) s += __shfl_xor(s, off, 16);
    ri[r] = 1.0f / s;
  }

  // stage embT over dead K/V area (all chunk readers passed the last barrier)
  {
    int d = tid & 63, ks0 = (tid >> 6) * 16;
    #pragma unroll
    for (int g = 0; g < 4; g++) {
      ushort4 u;
      #pragma unroll
      for (int kk = 0; kk < 4; kk++) {
        int k = ks0 + g*4 + kk;
        float val = (k < 32) ? vhe[k*512 + h*64 + d]
                  : (k < 48) ? vee[(k-32)*512 + h*64 + d] : 0.f;
        ((unsigned short*)&u)[kk] = f2h(val);
      }
      *reinterpret_cast<ushort4*>(&embT[d][ks0 + g*4]) = u;
    }
  }
  __syncthreads();

  // mass . emb via MFMA (rows are wave-private)
  {
    f16x8 am0, am1;
    #pragma unroll
    for (int j = 0; j < 8; j++) {
      am0[j] = (_Float16)vatt[w*16 + l15][quad*8 + j];
      float ve = 0.f;
      if (quad < 2) ve = veatt[w*16 + l15][quad*8 + j];
      am1[j] = (_Float16)ve;
    }
    #pragma unroll
    for (int nt = 0; nt < 4; nt++) {
      f16x8 be0 = *reinterpret_cast<const f16x8*>(&embT[nt*16 + l15][quad*8]);
      f16x8 be1 = *reinterpret_cast<const f16x8*>(&embT[nt*16 + l15][32 + quad*8]);
      Oacc[nt] = __builtin_amdgcn_mfma_f32_16x16x32_f16(am0, be0, Oacc[nt], 0, 0, 0);
      Oacc[nt] = __builtin_amdgcn_mfma_f32_16x16x32_f16(am1, be1, Oacc[nt], 0, 0, 0);
    }
  }

  // normalize + store bf16
  #pragma unroll
  for (int nt = 0; nt < 4; nt++) {
    #pragma unroll
    for (int r = 0; r < 4; r++) {
      int srow = i0 + w*16 + quad*4 + r;
      outp_bf[(size_t)(b*512 + srow)*512 + h*64 + nt*16 + l15] = f2bf(Oacc[nt][r] * ri[r]);
    }
  }
}

// ---------------------------------------------------------------------------
// bf16 MFMA GEMM (output proj): plain row-major fp32 C.
// ---------------------------------------------------------------------------
__global__ __launch_bounds__(256) void out_mfma(
    const unsigned short* __restrict__ X, const unsigned short* __restrict__ W,
    const float* __restrict__ bias, float* __restrict__ Y)
{
  __shared__ unsigned short As[128][40];
  __shared__ unsigned short Bs[128][40];
  const int tid = threadIdx.x;
  const int m0 = blockIdx.x * 128;
  const int n0 = blockIdx.y * 128;
  const int lane = tid & 63;
  const int w = tid >> 6;
  const int wr = w >> 1, wc = w & 1;
  const int l15 = lane & 15, quad = lane >> 4;

  const int srow = tid & 127;
  const unsigned short* srcrow = (tid < 128) ? &X[(size_t)(m0 + srow) * 512]
                                             : &W[(size_t)(n0 + srow) * 512];
  unsigned short* dstrow = (tid < 128) ? As[srow] : Bs[srow];

  f32x4 acc[4][4];
  #pragma unroll
  for (int i = 0; i < 4; i++)
    #pragma unroll
    for (int j = 0; j < 4; j++) acc[i][j] = (f32x4){0.f, 0.f, 0.f, 0.f};

  for (int k0 = 0; k0 < 512; k0 += 32) {
    #pragma unroll
    for (int u = 0; u < 4; u++) {
      uint4 t4 = *reinterpret_cast<const uint4*>(&srcrow[k0 + u * 8]);
      *reinterpret_cast<uint4*>(&dstrow[u * 8]) = t4;
    }
    __syncthreads();
    bf16x8 af[4], bfr[4];
    #pragma unroll
    for (int mt = 0; mt < 4; mt++)
      af[mt] = *reinterpret_cast<const bf16x8*>(&As[wr * 64 + mt * 16 + l15][quad * 8]);
    #pragma unroll
    for (int nt = 0; nt < 4; nt++)
      bfr[nt] = *reinterpret_cast<const bf16x8*>(&Bs[wc * 64 + nt * 16 + l15][quad * 8]);
    #pragma unroll
    for (int mt = 0; mt < 4; mt++)
      #pragma unroll
      for (int nt = 0; nt < 4; nt++)
        acc[mt][nt] = __builtin_amdgcn_mfma_f32_16x16x32_bf16(
            af[mt], bfr[nt], acc[mt][nt], 0, 0, 0);
    __syncthreads();
  }

  float bn[4];
  #pragma unroll
  for (int nt = 0; nt < 4; nt++)
    bn[nt] = bias[n0 + wc * 64 + nt * 16 + l15];
  #pragma unroll
  for (int mt = 0; mt < 4; mt++) {
    #pragma unroll
    for (int r = 0; r < 4; r++) {
      int m = m0 + wr * 64 + mt * 16 + quad * 4 + r;
      #pragma unroll
      for (int nt = 0; nt < 4; nt++) {
        int n = n0 + wc * 64 + nt * 16 + l15;
        Y[(size_t)m * 512 + n] = acc[mt][nt][r] + bn[nt];
      }
    }
  }
}

// ---------------------------------------------------------------------------
extern "C" void kernel_launch(void* const* d_in, const int* in_sizes, int n_in,
                              void* d_out, int out_size, void* d_ws, size_t ws_size,
                              hipStream_t stream) {
  (void)in_sizes; (void)n_in; (void)out_size; (void)ws_size;
  const float* q    = (const float*)d_in[0];
  const float* k    = (const float*)d_in[1];
  const float* v    = (const float*)d_in[2];
  const float* qhe  = (const float*)d_in[3];
  const float* qee  = (const float*)d_in[4];
  const float* khe  = (const float*)d_in[5];
  const float* kee  = (const float*)d_in[6];
  const float* vhe  = (const float*)d_in[7];
  const float* vee  = (const float*)d_in[8];
  const int*  dist  = (const int*)d_in[9];
  const int*  edge  = (const int*)d_in[10];
  const float* Wq = (const float*)d_in[11];
  const float* bq = (const float*)d_in[12];
  const float* Wk = (const float*)d_in[13];
  const float* bk = (const float*)d_in[14];
  const float* Wv = (const float*)d_in[15];
  const float* bv = (const float*)d_in[16];
  const float* Wo = (const float*)d_in[17];
  const float* bo = (const float*)d_in[18];

  // ---- workspace layout (bytes), total 90,177,536 ----
  char* ws = (char*)d_ws;
  unsigned short* qh16 = (unsigned short*)(ws + 0);          // 8,388,608 B
  unsigned short* kh16 = (unsigned short*)(ws + 8388608);    // 8,388,608
  unsigned short* vht  = (unsigned short*)(ws + 16777216);   // 8,388,608
  float* Aq  = (float*)(ws + 25165824);                      // 8,388,608
  float* Bkh = (float*)(ws + 33554432);                      // 8,388,608
  float* QKe = (float*)(ws + 41943040);                      // 4,194,304
  unsigned short* pidx = (unsigned short*)(ws + 46137344);   // 8,388,608
  unsigned short* q_bf = (unsigned short*)(ws + 54525952);   // 8,388,608
  unsigned short* k_bf = (unsigned short*)(ws + 62914560);   // 8,388,608
  unsigned short* v_bf = (unsigned short*)(ws + 71303168);   // 8,388,608
  unsigned short* outp_bf = (unsigned short*)(ws + 79691776);// 8,388,608
  unsigned short* wq_bf = (unsigned short*)(ws + 88080384);  // 524,288
  unsigned short* wk_bf = (unsigned short*)(ws + 88604672);
  unsigned short* wv_bf = (unsigned short*)(ws + 89128960);
  unsigned short* wo_bf = (unsigned short*)(ws + 89653248);  // ends 90,177,536

  dim3 blk(256);
  hipLaunchKernelGGL(convert_bf16, dim3(13312), blk, 0, stream,
                     q, k, v, Wq, Wk, Wv, Wo,
                     q_bf, k_bf, v_bf, wq_bf, wk_bf, wv_bf, wo_bf);
  hipLaunchKernelGGL(pack_idx, dim3(2048), dim3(64), 0, stream, dist, edge, pidx);
  dim3 gGemm(64, 4);
  hipLaunchKernelGGL(proj_qk, gGemm, blk, 0, stream, q_bf, wq_bf, bq, qh16);
  hipLaunchKernelGGL(proj_qk, gGemm, blk, 0, stream, k_bf, wk_bf, bk, kh16);
  hipLaunchKernelGGL(proj_v,  gGemm, blk, 0, stream, v_bf, wv_bf, bv, vht);
  hipLaunchKernelGGL(table_kernel, dim3(512), blk, 0, stream,
                     qh16, kh16, qhe, qee, khe, kee, Aq, QKe, Bkh);
  hipLaunchKernelGGL(attn_mfma, dim3(1024), blk, 0, stream,
                     qh16, kh16, vht, Aq, QKe, Bkh, vhe, vee, pidx, outp_bf);
  hipLaunchKernelGGL(out_mfma, gGemm, blk, 0, stream,
                     outp_bf, wo_bf, bo, (float*)d_out);
}